// Round 2
// baseline (1498.336 us; speedup 1.0000x reference)
//
#include <hip/hip_runtime.h>
#include <hip/hip_bf16.h>
#include <stdint.h>

#define DIM 128
#define NBLK 8
#define BS 16
#define NREL 8
#define NPB 32          // nodes per bucket (owner-computes granularity)
#define NPB_SHIFT 5

typedef unsigned int u32;
typedef unsigned long long u64;

// ---------------------------------------------------------------------------
// node_keep_mask dtype detection (worked in round 1, keep verbatim).
//   mode 0 = int32, 1 = uint8, 2 = uint16/bf16, 3 = float32
// ---------------------------------------------------------------------------
__global__ void detect_mask_kernel(const unsigned char* __restrict__ m,
                                   int* __restrict__ mode_out) {
    if (threadIdx.x != 0 || blockIdx.x != 0) return;
    bool f3f_pos1 = false, f3f = false, odd_nz = false;
    for (int i = 0; i < 512; ++i) {
        unsigned char b = m[i];
        if (b == 0x3F) { f3f = true; if ((i & 3) == 1) f3f_pos1 = true; }
        if ((i & 1) == 1 && b != 0) odd_nz = true;
    }
    int mode;
    if (f3f_pos1)      mode = 2;
    else if (f3f)      mode = 3;
    else if (odd_nz)   mode = 1;
    else               mode = 0;
    *mode_out = mode;
}

__device__ __forceinline__ bool mask_keep(const void* mask, int n, int mode) {
    switch (mode) {
        case 0:  return ((const int*)mask)[n] != 0;
        case 1:  return ((const unsigned char*)mask)[n] != 0;
        case 2:  return ((const unsigned short*)mask)[n] != 0;
        default: return ((const float*)mask)[n] != 0.0f;
    }
}

// ---------------------------------------------------------------------------
// Phase 0: zero the sub-bucket counters (ws is re-poisoned every launch).
// ---------------------------------------------------------------------------
__global__ void zero_kernel(int* __restrict__ p, int n) {
    int i = blockIdx.x * blockDim.x + threadIdx.x;
    if (i < n) p[i] = 0;
}

// ---------------------------------------------------------------------------
// Phase 1: count endpoint-messages per (bucket, relation).
// Only int atomics (3.2M over 12.5K counters) — cheap even write-through.
// ---------------------------------------------------------------------------
__global__ void count_kernel(const int* __restrict__ src, const int* __restrict__ tgt,
                             const int* __restrict__ et, int* __restrict__ cnt, int nE) {
    int e = blockIdx.x * 256 + threadIdx.x;
    if (e >= nE) return;
    int s = src[e], t = tgt[e], r = et[e];
    atomicAdd(&cnt[((t >> NPB_SHIFT) << 3) + r], 1);   // fwd message owned by t
    atomicAdd(&cnt[((s >> NPB_SHIFT) << 3) + r], 1);   // bwd message owned by s
}

// ---------------------------------------------------------------------------
// Phase 2: exclusive scan of counters (single 256-thread WG).
// ---------------------------------------------------------------------------
__global__ void scan_kernel(const int* __restrict__ cnt, int* __restrict__ off,
                            int* __restrict__ cursor, int nsb) {
    __shared__ int sums[256];
    const int t = threadIdx.x;
    const int ch = (nsb + 255) >> 8;
    const int lo = t * ch;
    const int hi = min(lo + ch, nsb);
    int s = 0;
    for (int i = lo; i < hi; ++i) s += cnt[i];
    sums[t] = s;
    __syncthreads();
    const int own = s;
    for (int o = 1; o < 256; o <<= 1) {
        int u = (t >= o) ? sums[t - o] : 0;
        __syncthreads();
        sums[t] += u;
        __syncthreads();
    }
    int run = sums[t] - own;                 // exclusive prefix at chunk start
    for (int i = lo; i < hi; ++i) {
        off[i] = run; cursor[i] = run; run += cnt[i];
    }
    if (t == 255) off[nsb] = sums[255];
}

// ---------------------------------------------------------------------------
// Phase 3: scatter packed entries. entry = w(f32)<<32 | owner_local<<16 | other
// ---------------------------------------------------------------------------
__global__ void scatter_kernel(const int* __restrict__ src, const int* __restrict__ tgt,
                               const int* __restrict__ et, const float* __restrict__ ew,
                               int* __restrict__ cursor, u64* __restrict__ entries, int nE) {
    int e = blockIdx.x * 256 + threadIdx.x;
    if (e >= nE) return;
    int s = src[e], t = tgt[e], r = et[e];
    u64 wb = ((u64)__float_as_uint(ew[e])) << 32;
    int p1 = atomicAdd(&cursor[((t >> NPB_SHIFT) << 3) + r], 1);
    entries[p1] = wb | (u32)s | ((u32)(t & (NPB - 1)) << 16);
    int p2 = atomicAdd(&cursor[((s >> NPB_SHIFT) << 3) + r], 1);
    entries[p2] = wb | (u32)t | ((u32)(s & (NPB - 1)) << 16);
}

// ---------------------------------------------------------------------------
// Phase 4: per-bucket owner-computes. 512 threads = 4 entry-lanes x 128 dims.
// LDS acc[32][128] (16 KB). Self transform + mask fused; relation-segmented
// message loop keeps the 16 B-column weights in registers; x rows gathered
// directly as broadcast float4 loads (L2/LLC-resident). No global atomics.
// ---------------------------------------------------------------------------
__launch_bounds__(512, 4)
__global__ void bucket_kernel(const float* __restrict__ x,
                              const float* __restrict__ blocks,
                              const void* __restrict__ mask,
                              const int* __restrict__ mode_p,
                              const int* __restrict__ off,
                              const u64* __restrict__ entries,
                              float* __restrict__ out,
                              int n_nodes) {
    __shared__ float acc[NPB][DIM];
    const int tid   = threadIdx.x;
    const int local = tid >> 7;            // 0..3 : which entry in the 4-group
    const int d     = tid & (DIM - 1);     // output dim
    const int blk   = d >> 4, j = d & 15;
    const int b     = blockIdx.x;
    const int nb0   = b << NPB_SHIFT;
    const int mode  = *mode_p;

    // --- self transform (initializes acc rows for owned nodes) ---
    for (int it = 0; it < NPB / 4; ++it) {
        const int ln = local + (it << 2);
        const int n  = nb0 + ln;
        if (n < n_nodes) {
            const float4* xp = (const float4*)(x + ((size_t)n << 7) + (blk << 4));
            const float4 a0 = xp[0], a1 = xp[1], a2 = xp[2], a3 = xp[3];
            const float* Bp = blocks + ((NREL * NBLK + blk) << 8) + j;
            float m = a0.x*Bp[0]   + a0.y*Bp[16]  + a0.z*Bp[32]  + a0.w*Bp[48]
                    + a1.x*Bp[64]  + a1.y*Bp[80]  + a1.z*Bp[96]  + a1.w*Bp[112]
                    + a2.x*Bp[128] + a2.y*Bp[144] + a2.z*Bp[160] + a2.w*Bp[176]
                    + a3.x*Bp[192] + a3.y*Bp[208] + a3.z*Bp[224] + a3.w*Bp[240];
            acc[ln][d] = mask_keep(mask, n, mode) ? m : 0.0f;
        }
    }
    __syncthreads();

    // --- message accumulation, segmented by relation ---
    const int sbase = b << 3;
    for (int r = 0; r < NREL; ++r) {
        const float* Bp = blocks + (((r << 3) + blk) << 8) + j;
        float bc[16];
        #pragma unroll
        for (int i = 0; i < 16; ++i) bc[i] = Bp[i << 4];
        const int st = off[sbase + r];
        const int en = off[sbase + r + 1];
        for (int idx = st + local; idx < en; idx += 4) {
            const u64 ent  = entries[idx];
            const float w  = __uint_as_float((u32)(ent >> 32));
            const int other = (int)(ent & 0xFFFFu);
            const int ol    = (int)((ent >> 16) & (NPB - 1));
            const float4* xp = (const float4*)(x + ((size_t)other << 7) + (blk << 4));
            const float4 a0 = xp[0], a1 = xp[1], a2 = xp[2], a3 = xp[3];
            float m = a0.x*bc[0]  + a0.y*bc[1]  + a0.z*bc[2]  + a0.w*bc[3]
                    + a1.x*bc[4]  + a1.y*bc[5]  + a1.z*bc[6]  + a1.w*bc[7]
                    + a2.x*bc[8]  + a2.y*bc[9]  + a2.z*bc[10] + a2.w*bc[11]
                    + a3.x*bc[12] + a3.y*bc[13] + a3.z*bc[14] + a3.w*bc[15];
            atomicAdd(&acc[ol][d], m * w);   // ds_add_f32, conflict-free banks
        }
    }
    __syncthreads();

    // --- coalesced writeout ---
    for (int it = 0; it < NPB / 4; ++it) {
        const int ln = local + (it << 2);
        const int n  = nb0 + ln;
        if (n < n_nodes) out[((size_t)n << 7) + d] = acc[ln][d];
    }
}

// ---------------------------------------------------------------------------
// Fallback path (round-1 kernels): used only if ws too small / nodes >= 65536.
// ---------------------------------------------------------------------------
__device__ __forceinline__ void atomAddF(float* p, float v) { unsafeAtomicAdd(p, v); }

__launch_bounds__(256)
__global__ void self_kernel(const float* __restrict__ x, const float* __restrict__ blocks,
                            const void* __restrict__ mask, const int* __restrict__ mode_p,
                            float* __restrict__ out, int n_nodes) {
    __shared__ float xs[2][DIM];
    const int mode  = *mode_p;
    const int local = threadIdx.x >> 7;
    const int d     = threadIdx.x & (DIM - 1);
    const int n     = blockIdx.x * 2 + local;
    const bool ok   = (n < n_nodes);
    if (ok) xs[local][d] = x[n * DIM + d];
    __syncthreads();
    if (!ok) return;
    const int b = d >> 4, j = d & (BS - 1);
    const float* B  = blocks + (8 * NBLK + b) * (BS * BS) + j;
    const float* xr = &xs[local][b * BS];
    float acc = 0.0f;
    #pragma unroll
    for (int i = 0; i < BS; ++i) acc += xr[i] * B[i * BS];
    out[n * DIM + d] = mask_keep(mask, n, mode) ? acc : 0.0f;
}

__launch_bounds__(256)
__global__ void edge_kernel(const float* __restrict__ x, const float* __restrict__ blocks,
                            const int* __restrict__ source, const int* __restrict__ target,
                            const int* __restrict__ etype, const float* __restrict__ ew,
                            float* __restrict__ out, int n_edges) {
    __shared__ float sx[2][2][DIM];
    const int local = threadIdx.x >> 7;
    const int d     = threadIdx.x & (DIM - 1);
    const int e     = blockIdx.x * 2 + local;
    const bool ok   = (e < n_edges);
    int s = 0, t = 0, r = 0;
    float w = 0.0f;
    if (ok) {
        s = source[e]; t = target[e]; r = etype[e]; w = ew[e];
        sx[local][0][d] = x[s * DIM + d];
        sx[local][1][d] = x[t * DIM + d];
    }
    __syncthreads();
    if (!ok) return;
    const int b = d >> 4, j = d & (BS - 1);
    const float* B   = blocks + (r * NBLK + b) * (BS * BS) + j;
    const float* xsr = &sx[local][0][b * BS];
    const float* xtr = &sx[local][1][b * BS];
    float af = 0.0f, ab = 0.0f;
    #pragma unroll
    for (int i = 0; i < BS; ++i) {
        const float bw = B[i * BS];
        af += xsr[i] * bw;
        ab += xtr[i] * bw;
    }
    atomAddF(&out[t * DIM + d], af * w);
    atomAddF(&out[s * DIM + d], ab * w);
}

// ---------------------------------------------------------------------------
extern "C" void kernel_launch(void* const* d_in, const int* in_sizes, int n_in,
                              void* d_out, int out_size, void* d_ws, size_t ws_size,
                              hipStream_t stream) {
    const float* x      = (const float*)d_in[0];
    const float* blocks = (const float*)d_in[1];
    const void*  mask   = d_in[2];
    const int*   source = (const int*)d_in[3];
    const int*   target = (const int*)d_in[4];
    const int*   etype  = (const int*)d_in[5];
    const float* ew     = (const float*)d_in[6];
    float*       out    = (float*)d_out;

    const int n_nodes = in_sizes[0] / DIM;
    const int n_edges = in_sizes[3];
    const int NB  = (n_nodes + NPB - 1) >> NPB_SHIFT;
    const int NSB = NB << 3;

    // ws layout
    char* ws = (char*)d_ws;
    const size_t o_cnt = 256;
    const size_t o_off = o_cnt + (((size_t)NSB * 4 + 63) & ~(size_t)63);
    const size_t o_cur = o_off + (((size_t)(NSB + 1) * 4 + 63) & ~(size_t)63);
    const size_t o_ent = (o_cur + (size_t)NSB * 4 + 255) & ~(size_t)255;
    const size_t need  = o_ent + (size_t)2 * n_edges * 8;

    int* mode = (int*)ws;
    hipLaunchKernelGGL(detect_mask_kernel, dim3(1), dim3(64), 0, stream,
                       (const unsigned char*)mask, mode);

    if (need <= ws_size && n_nodes <= 65535) {
        int* cnt    = (int*)(ws + o_cnt);
        int* offp   = (int*)(ws + o_off);
        int* cursor = (int*)(ws + o_cur);
        u64* ent    = (u64*)(ws + o_ent);

        hipLaunchKernelGGL(zero_kernel, dim3((NSB + 1023) / 1024), dim3(1024), 0, stream,
                           cnt, NSB);
        hipLaunchKernelGGL(count_kernel, dim3((n_edges + 255) / 256), dim3(256), 0, stream,
                           source, target, etype, cnt, n_edges);
        hipLaunchKernelGGL(scan_kernel, dim3(1), dim3(256), 0, stream,
                           cnt, offp, cursor, NSB);
        hipLaunchKernelGGL(scatter_kernel, dim3((n_edges + 255) / 256), dim3(256), 0, stream,
                           source, target, etype, ew, cursor, ent, n_edges);
        hipLaunchKernelGGL(bucket_kernel, dim3(NB), dim3(512), 0, stream,
                           x, blocks, mask, mode, offp, ent, out, n_nodes);
    } else {
        hipLaunchKernelGGL(self_kernel, dim3((n_nodes + 1) / 2), dim3(256), 0, stream,
                           x, blocks, mask, mode, out, n_nodes);
        hipLaunchKernelGGL(edge_kernel, dim3((n_edges + 1) / 2), dim3(256), 0, stream,
                           x, blocks, source, target, etype, ew, out, n_edges);
    }
}

// Round 5
// 1491.337 us; speedup vs baseline: 1.0047x; 1.0047x over previous
//
#include <hip/hip_runtime.h>
#include <hip/hip_bf16.h>
#include <stdint.h>

#define DIM 128
#define NBLK 8
#define BS 16
#define NREL 8
#define NPB 16          // nodes per bucket (owner-computes granularity)
#define NPB_SHIFT 4
#define ENT_STAGE 256   // entries staged in LDS per chunk

typedef unsigned int u32;
typedef unsigned long long u64;

// ---------------------------------------------------------------------------
// node_keep_mask dtype detection (stable since round 1).
//   mode 0 = int32, 1 = uint8, 2 = uint16/bf16, 3 = float32
// ---------------------------------------------------------------------------
__global__ void detect_mask_kernel(const unsigned char* __restrict__ m,
                                   int* __restrict__ mode_out) {
    if (threadIdx.x != 0 || blockIdx.x != 0) return;
    bool f3f_pos1 = false, f3f = false, odd_nz = false;
    for (int i = 0; i < 512; ++i) {
        unsigned char b = m[i];
        if (b == 0x3F) { f3f = true; if ((i & 3) == 1) f3f_pos1 = true; }
        if ((i & 1) == 1 && b != 0) odd_nz = true;
    }
    int mode;
    if (f3f_pos1)      mode = 2;
    else if (f3f)      mode = 3;
    else if (odd_nz)   mode = 1;
    else               mode = 0;
    *mode_out = mode;
}

__device__ __forceinline__ bool mask_keep(const void* mask, int n, int mode) {
    switch (mode) {
        case 0:  return ((const int*)mask)[n] != 0;
        case 1:  return ((const unsigned char*)mask)[n] != 0;
        case 2:  return ((const unsigned short*)mask)[n] != 0;
        default: return ((const float*)mask)[n] != 0.0f;
    }
}

// ---------------------------------------------------------------------------
__global__ void zero_kernel(int* __restrict__ p, int n) {
    int i = blockIdx.x * blockDim.x + threadIdx.x;
    if (i < n) p[i] = 0;
}

__global__ void count_kernel(const int* __restrict__ src, const int* __restrict__ tgt,
                             const int* __restrict__ et, int* __restrict__ cnt, int nE) {
    int e = blockIdx.x * 256 + threadIdx.x;
    if (e >= nE) return;
    int s = src[e], t = tgt[e], r = et[e];
    atomicAdd(&cnt[((t >> NPB_SHIFT) << 3) + r], 1);   // fwd message owned by t
    atomicAdd(&cnt[((s >> NPB_SHIFT) << 3) + r], 1);   // bwd message owned by s
}

__global__ void scan_kernel(const int* __restrict__ cnt, int* __restrict__ off,
                            int* __restrict__ cursor, int nsb) {
    __shared__ int sums[256];
    const int t = threadIdx.x;
    const int ch = (nsb + 255) >> 8;
    const int lo = t * ch;
    const int hi = min(lo + ch, nsb);
    int s = 0;
    for (int i = lo; i < hi; ++i) s += cnt[i];
    sums[t] = s;
    __syncthreads();
    const int own = s;
    for (int o = 1; o < 256; o <<= 1) {
        int u = (t >= o) ? sums[t - o] : 0;
        __syncthreads();
        sums[t] += u;
        __syncthreads();
    }
    int run = sums[t] - own;
    for (int i = lo; i < hi; ++i) {
        off[i] = run; cursor[i] = run; run += cnt[i];
    }
    if (t == 255) off[nsb] = sums[255];
}

// entry = w(f32)<<32 | owner_local(4b)<<16 | other(16b)
__global__ void scatter_kernel(const int* __restrict__ src, const int* __restrict__ tgt,
                               const int* __restrict__ et, const float* __restrict__ ew,
                               int* __restrict__ cursor, u64* __restrict__ entries, int nE) {
    int e = blockIdx.x * 256 + threadIdx.x;
    if (e >= nE) return;
    int s = src[e], t = tgt[e], r = et[e];
    u64 wb = ((u64)__float_as_uint(ew[e])) << 32;
    int p1 = atomicAdd(&cursor[((t >> NPB_SHIFT) << 3) + r], 1);
    entries[p1] = wb | (u32)s | ((u32)(t & (NPB - 1)) << 16);
    int p2 = atomicAdd(&cursor[((s >> NPB_SHIFT) << 3) + r], 1);
    entries[p2] = wb | (u32)t | ((u32)(s & (NPB - 1)) << 16);
}

// ---------------------------------------------------------------------------
// Bucket kernel v2. 256 threads = 2 entry-lanes x 128 dims; bucket of 16
// nodes; acc[16][128] = 8 KB LDS. Entries LDS-staged (coalesced); B column
// pinned in VGPRs via empty asm (round-2 showed the compiler rematerializing
// it into the hot loop at VGPR=32, serializing all loads); 4-entry unroll
// issues 16 independent float4 gathers before any FMA chain.
// ---------------------------------------------------------------------------
#define LOADX(E, X0, X1, X2, X3) {                                            \
    const float4* xp_ = (const float4*)(x + (((size_t)((E) & 0xFFFFu)) << 7)  \
                                          + (blk << 4));                      \
    X0 = xp_[0]; X1 = xp_[1]; X2 = xp_[2]; X3 = xp_[3]; }

#define DOT16(X0, X1, X2, X3)                                                 \
    (X0.x*bc[0]  + X0.y*bc[1]  + X0.z*bc[2]  + X0.w*bc[3] +                   \
     X1.x*bc[4]  + X1.y*bc[5]  + X1.z*bc[6]  + X1.w*bc[7] +                   \
     X2.x*bc[8]  + X2.y*bc[9]  + X2.z*bc[10] + X2.w*bc[11] +                  \
     X3.x*bc[12] + X3.y*bc[13] + X3.z*bc[14] + X3.w*bc[15])

__launch_bounds__(256, 4)
__global__ void bucket_kernel(const float* __restrict__ x,
                              const float* __restrict__ blocks,
                              const void* __restrict__ mask,
                              const int* __restrict__ mode_p,
                              const int* __restrict__ off,
                              const u64* __restrict__ entries,
                              float* __restrict__ out,
                              int n_nodes) {
    __shared__ float acc[NPB][DIM];
    __shared__ u64 ent_s[ENT_STAGE];
    const int tid   = threadIdx.x;
    const int local = tid >> 7;            // 0..1
    const int d     = tid & (DIM - 1);
    const int blk   = d >> 4, j = d & 15;
    const int b     = blockIdx.x;
    const int nb0   = b << NPB_SHIFT;
    const int mode  = *mode_p;

    // --- self transform (B column for blocks[8] pinned in regs) ---
    {
        const float* Bp = blocks + ((NREL * NBLK + blk) << 8) + j;
        float bc[16];
        #pragma unroll
        for (int i = 0; i < 16; ++i) bc[i] = Bp[i << 4];
        #pragma unroll
        for (int i = 0; i < 16; ++i) asm volatile("" : "+v"(bc[i]));
        #pragma unroll
        for (int it = 0; it < NPB / 2; ++it) {
            const int ln = (it << 1) + local;
            const int n  = nb0 + ln;
            if (n < n_nodes) {
                float4 a0, a1, a2, a3;
                const float4* xp_ = (const float4*)(x + ((size_t)n << 7) + (blk << 4));
                a0 = xp_[0]; a1 = xp_[1]; a2 = xp_[2]; a3 = xp_[3];
                const float m = DOT16(a0, a1, a2, a3);
                acc[ln][d] = mask_keep(mask, n, mode) ? m : 0.0f;
            }
        }
    }
    __syncthreads();

    // --- message accumulation, relation-segmented ---
    const int sbase = b << 3;
    for (int r = 0; r < NREL; ++r) {
        const float* Bp = blocks + (((r << 3) + blk) << 8) + j;
        float bc[16];
        #pragma unroll
        for (int i = 0; i < 16; ++i) bc[i] = Bp[i << 4];
        #pragma unroll
        for (int i = 0; i < 16; ++i) asm volatile("" : "+v"(bc[i]));

        const int st = off[sbase + r];
        const int en = off[sbase + r + 1];
        for (int base = st; base < en; base += ENT_STAGE) {
            const int m = min(ENT_STAGE, en - base);
            __syncthreads();                       // ent_s reuse guard
            if (tid < m) ent_s[tid] = entries[base + tid];
            __syncthreads();

            int k = local;
            for (; k + 6 < m; k += 8) {            // 4 entries per group-iter
                const u64 e0 = ent_s[k], e1 = ent_s[k + 2],
                          e2 = ent_s[k + 4], e3 = ent_s[k + 6];
                float4 a0, a1, a2, a3, b0, b1, b2, b3,
                       c0, c1, c2, c3, f0, f1, f2, f3;
                LOADX(e0, a0, a1, a2, a3);
                LOADX(e1, b0, b1, b2, b3);
                LOADX(e2, c0, c1, c2, c3);
                LOADX(e3, f0, f1, f2, f3);
                const float w0 = __uint_as_float((u32)(e0 >> 32));
                const float w1 = __uint_as_float((u32)(e1 >> 32));
                const float w2 = __uint_as_float((u32)(e2 >> 32));
                const float w3 = __uint_as_float((u32)(e3 >> 32));
                const int o0 = (int)((e0 >> 16) & (NPB - 1));
                const int o1 = (int)((e1 >> 16) & (NPB - 1));
                const int o2 = (int)((e2 >> 16) & (NPB - 1));
                const int o3 = (int)((e3 >> 16) & (NPB - 1));
                atomicAdd(&acc[o0][d], DOT16(a0, a1, a2, a3) * w0);
                atomicAdd(&acc[o1][d], DOT16(b0, b1, b2, b3) * w1);
                atomicAdd(&acc[o2][d], DOT16(c0, c1, c2, c3) * w2);
                atomicAdd(&acc[o3][d], DOT16(f0, f1, f2, f3) * w3);
            }
            for (; k < m; k += 2) {                // tail
                const u64 e0 = ent_s[k];
                float4 a0, a1, a2, a3;
                LOADX(e0, a0, a1, a2, a3);
                const float w0 = __uint_as_float((u32)(e0 >> 32));
                const int   o0 = (int)((e0 >> 16) & (NPB - 1));
                atomicAdd(&acc[o0][d], DOT16(a0, a1, a2, a3) * w0);
            }
        }
    }
    __syncthreads();

    // --- coalesced writeout ---
    #pragma unroll
    for (int it = 0; it < NPB / 2; ++it) {
        const int ln = (it << 1) + local;
        const int n  = nb0 + ln;
        if (n < n_nodes) out[((size_t)n << 7) + d] = acc[ln][d];
    }
}

// ---------------------------------------------------------------------------
// Fallback path (round-1 kernels, 775 µs known-good).
// ---------------------------------------------------------------------------
__device__ __forceinline__ void atomAddF(float* p, float v) { unsafeAtomicAdd(p, v); }

__launch_bounds__(256)
__global__ void self_kernel(const float* __restrict__ x, const float* __restrict__ blocks,
                            const void* __restrict__ mask, const int* __restrict__ mode_p,
                            float* __restrict__ out, int n_nodes) {
    __shared__ float xs[2][DIM];
    const int mode  = *mode_p;
    const int local = threadIdx.x >> 7;
    const int d     = threadIdx.x & (DIM - 1);
    const int n     = blockIdx.x * 2 + local;
    const bool ok   = (n < n_nodes);
    if (ok) xs[local][d] = x[n * DIM + d];
    __syncthreads();
    if (!ok) return;
    const int b = d >> 4, j = d & (BS - 1);
    const float* B  = blocks + (8 * NBLK + b) * (BS * BS) + j;
    const float* xr = &xs[local][b * BS];
    float acc = 0.0f;
    #pragma unroll
    for (int i = 0; i < BS; ++i) acc += xr[i] * B[i * BS];
    out[n * DIM + d] = mask_keep(mask, n, mode) ? acc : 0.0f;
}

__launch_bounds__(256)
__global__ void edge_kernel(const float* __restrict__ x, const float* __restrict__ blocks,
                            const int* __restrict__ source, const int* __restrict__ target,
                            const int* __restrict__ etype, const float* __restrict__ ew,
                            float* __restrict__ out, int n_edges) {
    __shared__ float sx[2][2][DIM];
    const int local = threadIdx.x >> 7;
    const int d     = threadIdx.x & (DIM - 1);
    const int e     = blockIdx.x * 2 + local;
    const bool ok   = (e < n_edges);
    int s = 0, t = 0, r = 0;
    float w = 0.0f;
    if (ok) {
        s = source[e]; t = target[e]; r = etype[e]; w = ew[e];
        sx[local][0][d] = x[s * DIM + d];
        sx[local][1][d] = x[t * DIM + d];
    }
    __syncthreads();
    if (!ok) return;
    const int b = d >> 4, j = d & (BS - 1);
    const float* B   = blocks + (r * NBLK + b) * (BS * BS) + j;
    const float* xsr = &sx[local][0][b * BS];
    const float* xtr = &sx[local][1][b * BS];
    float af = 0.0f, ab = 0.0f;
    #pragma unroll
    for (int i = 0; i < BS; ++i) {
        const float bw = B[i * BS];
        af += xsr[i] * bw;
        ab += xtr[i] * bw;
    }
    atomAddF(&out[t * DIM + d], af * w);
    atomAddF(&out[s * DIM + d], ab * w);
}

// ---------------------------------------------------------------------------
extern "C" void kernel_launch(void* const* d_in, const int* in_sizes, int n_in,
                              void* d_out, int out_size, void* d_ws, size_t ws_size,
                              hipStream_t stream) {
    const float* x      = (const float*)d_in[0];
    const float* blocks = (const float*)d_in[1];
    const void*  mask   = d_in[2];
    const int*   source = (const int*)d_in[3];
    const int*   target = (const int*)d_in[4];
    const int*   etype  = (const int*)d_in[5];
    const float* ew     = (const float*)d_in[6];
    float*       out    = (float*)d_out;

    const int n_nodes = in_sizes[0] / DIM;
    const int n_edges = in_sizes[3];
    const int NB  = (n_nodes + NPB - 1) >> NPB_SHIFT;
    const int NSB = NB << 3;

    // ws layout
    char* ws = (char*)d_ws;
    const size_t o_cnt = 256;
    const size_t o_off = o_cnt + (((size_t)NSB * 4 + 63) & ~(size_t)63);
    const size_t o_cur = o_off + (((size_t)(NSB + 1) * 4 + 63) & ~(size_t)63);
    const size_t o_ent = (o_cur + (size_t)NSB * 4 + 255) & ~(size_t)255;
    const size_t need  = o_ent + (size_t)2 * n_edges * 8;

    int* mode = (int*)ws;
    hipLaunchKernelGGL(detect_mask_kernel, dim3(1), dim3(64), 0, stream,
                       (const unsigned char*)mask, mode);

    if (need <= ws_size && n_nodes <= 65535) {
        int* cnt    = (int*)(ws + o_cnt);
        int* offp   = (int*)(ws + o_off);
        int* cursor = (int*)(ws + o_cur);
        u64* ent    = (u64*)(ws + o_ent);

        hipLaunchKernelGGL(zero_kernel, dim3((NSB + 1023) / 1024), dim3(1024), 0, stream,
                           cnt, NSB);
        hipLaunchKernelGGL(count_kernel, dim3((n_edges + 255) / 256), dim3(256), 0, stream,
                           source, target, etype, cnt, n_edges);
        hipLaunchKernelGGL(scan_kernel, dim3(1), dim3(256), 0, stream,
                           cnt, offp, cursor, NSB);
        hipLaunchKernelGGL(scatter_kernel, dim3((n_edges + 255) / 256), dim3(256), 0, stream,
                           source, target, etype, ew, cursor, ent, n_edges);
        hipLaunchKernelGGL(bucket_kernel, dim3(NB), dim3(256), 0, stream,
                           x, blocks, mask, mode, offp, ent, out, n_nodes);
    } else {
        hipLaunchKernelGGL(self_kernel, dim3((n_nodes + 1) / 2), dim3(256), 0, stream,
                           x, blocks, mask, mode, out, n_nodes);
        hipLaunchKernelGGL(edge_kernel, dim3((n_edges + 1) / 2), dim3(256), 0, stream,
                           x, blocks, source, target, etype, ew, out, n_edges);
    }
}